// Round 6
// baseline (239.253 us; speedup 1.0000x reference)
//
#include <hip/hip_runtime.h>

// Barrel shift right each 64-float row by S = sum_j shift[j]*2^(5-j)
// (shift entries exactly 0/1):  out[row][k] = (k>=S) ? data[row][k-S] : 0.
//
// Structure (best of R1-R5): aligned nt float4 loads (each byte read once),
// in-lane rotate + 4 ds_bpermute per row, nt stores. This round: exact-division
// branch-free main loop, unroll x4 (4 independent wrows, all loads issued
// before any consumer) to maximize outstanding VMEM per wave.
//
// Wave layout: 4 rows per wave, 16 lanes per row, float4 per lane.

typedef float f4 __attribute__((ext_vector_type(4)));

__device__ __forceinline__ f4 rowshift(f4 val, unsigned long long b,
                                       int g, int t16) {
    unsigned sub = (unsigned)(b >> (6 * g)) & 63u;
    int S = (int)(__brev(sub) >> 26);        // MSB-first control word
    int q0 = t16 * 4 - S;                    // first source position
    int t = q0 & 3;                          // row-uniform sub-word alignment

    // in-lane rotate-left of val by t: s[j] = val[(t+j)&3]
    bool b0 = (t & 1) != 0, b1 = (t & 2) != 0;
    float r0 = b1 ? val.z : val.x;
    float r1 = b1 ? val.w : val.y;
    float r2 = b1 ? val.x : val.z;
    float r3 = b1 ? val.y : val.w;
    float s0 = b0 ? r1 : r0;
    float s1 = b0 ? r2 : r1;
    float s2 = b0 ? r3 : r2;
    float s3 = b0 ? r0 : r3;

    int la0 = (q0    ) >> 2;  la0 = la0 < 0 ? 0 : la0;
    int la1 = (q0 + 1) >> 2;  la1 = la1 < 0 ? 0 : la1;
    int la2 = (q0 + 2) >> 2;  la2 = la2 < 0 ? 0 : la2;
    int la3 = (q0 + 3) >> 2;  la3 = la3 < 0 ? 0 : la3;
    int base = g * 16;

    float o0 = __shfl(s0, base + la0, 64);
    float o1 = __shfl(s1, base + la1, 64);
    float o2 = __shfl(s2, base + la2, 64);
    float o3 = __shfl(s3, base + la3, 64);

    f4 r;
    r.x = (q0 >= 0)  ? o0 : 0.0f;
    r.y = (q0 >= -1) ? o1 : 0.0f;
    r.z = (q0 >= -2) ? o2 : 0.0f;
    r.w = (q0 >= -3) ? o3 : 0.0f;
    return r;
}

__global__ __launch_bounds__(256)
void BarrelShifterRight64_exact(const float* __restrict__ data,
                                const float* __restrict__ shift,
                                float* __restrict__ out,
                                int nwrows) {
    constexpr int U = 4;
    const int lane = threadIdx.x & 63;
    const int wib  = threadIdx.x >> 6;
    const int wpb  = blockDim.x >> 6;
    const int nw   = gridDim.x * wpb;
    const int w0   = blockIdx.x * wpb + wib;

    const f4* __restrict__ d4 = (const f4*)data;
    f4* __restrict__       o4 = (f4*)out;

    const int g   = lane >> 4;
    const int t16 = lane & 15;
    const bool sl = lane < 24;

    const int stride = U * nw;
    const int niter  = nwrows / stride;   // exact by dispatch-side check

    // prologue: shift words for the first U wrows
    float sv0 = sl ? shift[(w0 + 0 * nw) * 24 + lane] : 0.0f;
    float sv1 = sl ? shift[(w0 + 1 * nw) * 24 + lane] : 0.0f;
    float sv2 = sl ? shift[(w0 + 2 * nw) * 24 + lane] : 0.0f;
    float sv3 = sl ? shift[(w0 + 3 * nw) * 24 + lane] : 0.0f;

    int w = w0;
    for (int it = 0; it < niter; ++it, w += stride) {
        unsigned long long b0 = __ballot(sv0 > 0.5f);
        unsigned long long b1 = __ballot(sv1 > 0.5f);
        unsigned long long b2 = __ballot(sv2 > 0.5f);
        unsigned long long b3 = __ballot(sv3 > 0.5f);

        // issue all 4 independent data loads back-to-back
        f4 v0 = __builtin_nontemporal_load(&d4[(w + 0 * nw) * 64 + lane]);
        f4 v1 = __builtin_nontemporal_load(&d4[(w + 1 * nw) * 64 + lane]);
        f4 v2 = __builtin_nontemporal_load(&d4[(w + 2 * nw) * 64 + lane]);
        f4 v3 = __builtin_nontemporal_load(&d4[(w + 3 * nw) * 64 + lane]);

        // prefetch next iteration's shift words (hidden under the data loads)
        const bool more = it + 1 < niter;
        const int  wn   = w + stride;
        sv0 = (sl && more) ? shift[(wn + 0 * nw) * 24 + lane] : 0.0f;
        sv1 = (sl && more) ? shift[(wn + 1 * nw) * 24 + lane] : 0.0f;
        sv2 = (sl && more) ? shift[(wn + 2 * nw) * 24 + lane] : 0.0f;
        sv3 = (sl && more) ? shift[(wn + 3 * nw) * 24 + lane] : 0.0f;

        f4 q0 = rowshift(v0, b0, g, t16);
        __builtin_nontemporal_store(q0, &o4[(w + 0 * nw) * 64 + lane]);
        f4 q1 = rowshift(v1, b1, g, t16);
        __builtin_nontemporal_store(q1, &o4[(w + 1 * nw) * 64 + lane]);
        f4 q2 = rowshift(v2, b2, g, t16);
        __builtin_nontemporal_store(q2, &o4[(w + 2 * nw) * 64 + lane]);
        f4 q3 = rowshift(v3, b3, g, t16);
        __builtin_nontemporal_store(q3, &o4[(w + 3 * nw) * 64 + lane]);
    }
}

__global__ __launch_bounds__(256)
void BarrelShifterRight64_generic(const float* __restrict__ data,
                                  const float* __restrict__ shift,
                                  float* __restrict__ out,
                                  int nwrows) {
    const int lane = threadIdx.x & 63;
    const int wib  = threadIdx.x >> 6;
    const int wpb  = blockDim.x >> 6;
    const int nw   = gridDim.x * wpb;
    const int w0   = blockIdx.x * wpb + wib;

    const f4* __restrict__ d4 = (const f4*)data;
    f4* __restrict__       o4 = (f4*)out;

    const int g   = lane >> 4;
    const int t16 = lane & 15;
    const bool sl = lane < 24;

    for (int w = w0; w < nwrows; w += nw) {
        float sv = sl ? shift[w * 24 + lane] : 0.0f;
        unsigned long long b = __ballot(sv > 0.5f);
        f4 v = __builtin_nontemporal_load(&d4[w * 64 + lane]);
        f4 o = rowshift(v, b, g, t16);
        __builtin_nontemporal_store(o, &o4[w * 64 + lane]);
    }
}

extern "C" void kernel_launch(void* const* d_in, const int* in_sizes, int n_in,
                              void* d_out, int out_size, void* d_ws, size_t ws_size,
                              hipStream_t stream) {
    const float* data  = (const float*)d_in[0];
    const float* shift = (const float*)d_in[1];
    float* out = (float*)d_out;

    const int nrows  = in_sizes[0] / 64;   // B
    const int nwrows = nrows / 4;          // 4 rows per wave

    const int block = 256;
    const int grid  = 2048;                // 8192 waves = 32/CU, full occupancy
    const int nw    = grid * (block / 64);

    if (nwrows % (4 * nw) == 0) {
        BarrelShifterRight64_exact<<<grid, block, 0, stream>>>(data, shift, out, nwrows);
    } else {
        BarrelShifterRight64_generic<<<grid, block, 0, stream>>>(data, shift, out, nwrows);
    }
}

// Round 7
// 224.647 us; speedup vs baseline: 1.0650x; 1.0650x over previous
//
#include <hip/hip_runtime.h>

// Barrel shift right each 64-float row by S = sum_j shift[j]*2^(5-j)
// (shift entries exactly 0/1):  out[row][k] = (k>=S) ? data[row][k-S] : 0.
//
// R3 structure verbatim (best: 203.2 us) with ONE change: stores are plain
// (L2 write-combined) instead of nontemporal. Loads stay nt (read-once).
//
// Wave layout: 4 rows per wave, 16 lanes per row, float4 per lane.
// S is row-uniform -> q0&3 is row-uniform: each source lane pre-rotates its
// float4 in-lane, then one ds_bpermute per output element. 4 shfl/row.

typedef float f4 __attribute__((ext_vector_type(4)));

__device__ __forceinline__ f4 rowshift(f4 val, unsigned long long b,
                                       int g, int t16) {
    unsigned sub = (unsigned)(b >> (6 * g)) & 63u;
    int S = (int)(__brev(sub) >> 26);        // MSB-first control word
    int q0 = t16 * 4 - S;                    // first source position
    int t = q0 & 3;                          // row-uniform sub-word alignment

    // in-lane rotate-left of val by t: s[j] = val[(t+j)&3]
    bool b0 = (t & 1) != 0, b1 = (t & 2) != 0;
    float r0 = b1 ? val.z : val.x;
    float r1 = b1 ? val.w : val.y;
    float r2 = b1 ? val.x : val.z;
    float r3 = b1 ? val.y : val.w;
    float s0 = b0 ? r1 : r0;
    float s1 = b0 ? r2 : r1;
    float s2 = b0 ? r3 : r2;
    float s3 = b0 ? r0 : r3;

    // source lane (within the row's 16 lanes) for each output element
    int la0 = (q0    ) >> 2;  la0 = la0 < 0 ? 0 : la0;
    int la1 = (q0 + 1) >> 2;  la1 = la1 < 0 ? 0 : la1;
    int la2 = (q0 + 2) >> 2;  la2 = la2 < 0 ? 0 : la2;
    int la3 = (q0 + 3) >> 2;  la3 = la3 < 0 ? 0 : la3;
    int base = g * 16;

    float o0 = __shfl(s0, base + la0, 64);
    float o1 = __shfl(s1, base + la1, 64);
    float o2 = __shfl(s2, base + la2, 64);
    float o3 = __shfl(s3, base + la3, 64);

    f4 r;
    r.x = (q0 >= 0)  ? o0 : 0.0f;
    r.y = (q0 >= -1) ? o1 : 0.0f;
    r.z = (q0 >= -2) ? o2 : 0.0f;
    r.w = (q0 >= -3) ? o3 : 0.0f;
    return r;
}

__global__ __launch_bounds__(256)
void BarrelShifterRight64_kernel(const float* __restrict__ data,
                                 const float* __restrict__ shift,
                                 float* __restrict__ out,
                                 int nwrows) {
    const int lane = threadIdx.x & 63;
    const int wib  = threadIdx.x >> 6;
    const int wpb  = blockDim.x >> 6;
    const int nw   = gridDim.x * wpb;
    const int w0   = blockIdx.x * wpb + wib;

    const f4* __restrict__ d4 = (const f4*)data;
    f4* __restrict__       o4 = (f4*)out;

    const int g   = lane >> 4;
    const int t16 = lane & 15;

    for (int w = w0; w < nwrows; w += 2 * nw) {
        const int w1 = w + nw;
        const bool have1 = w1 < nwrows;

        // issue both independent row-set loads up front (MLP)
        f4 vA = __builtin_nontemporal_load(&d4[w * 64 + lane]);
        float svA = (lane < 24) ? shift[w * 24 + lane] : 0.0f;

        f4 vB = (f4)(0.0f);
        float svB = 0.0f;
        if (have1) {
            vB  = __builtin_nontemporal_load(&d4[w1 * 64 + lane]);
            svB = (lane < 24) ? shift[w1 * 24 + lane] : 0.0f;
        }

        unsigned long long bA = __ballot(svA > 0.5f);
        f4 oA = rowshift(vA, bA, g, t16);
        o4[w * 64 + lane] = oA;                       // plain store (L2 WC)

        if (have1) {
            unsigned long long bB = __ballot(svB > 0.5f);
            f4 oB = rowshift(vB, bB, g, t16);
            o4[w1 * 64 + lane] = oB;                  // plain store
        }
    }
}

extern "C" void kernel_launch(void* const* d_in, const int* in_sizes, int n_in,
                              void* d_out, int out_size, void* d_ws, size_t ws_size,
                              hipStream_t stream) {
    const float* data  = (const float*)d_in[0];
    const float* shift = (const float*)d_in[1];
    float* out = (float*)d_out;

    const int nrows  = in_sizes[0] / 64;   // B
    const int nwrows = nrows / 4;          // 4 rows per wave

    const int block = 256;
    const int grid  = 2048;                // 8192 waves, grid-stride, unroll x2
    BarrelShifterRight64_kernel<<<grid, block, 0, stream>>>(data, shift, out, nwrows);
}

// Round 8
// 221.329 us; speedup vs baseline: 1.0810x; 1.0150x over previous
//
#include <hip/hip_runtime.h>

// Barrel shift right each 64-float row by S = sum_j shift[j]*2^(5-j)
// (shift entries exactly 0/1):  out[row][k] = (k>=S) ? data[row][k-S] : 0.
//
// Two-phase: (1) pre-pass folds shift (48 MiB) to 1 S-byte/row (2 MiB in d_ws);
// (2) main kernel = near-pure streaming copy with an in-wave permute:
//     per wrow: 1 uniform dword (4 S-codes) + 1 nt float4 load + 4 shfl + 1 nt store.
// Wave layout: 4 rows/wave, 16 lanes/row, float4/lane. nt on both big streams
// (R7 showed nt stores are +10%). Falls back to single-kernel R3 form if d_ws
// is too small.

typedef float f4 __attribute__((ext_vector_type(4)));

__device__ __forceinline__ f4 rowshift_S(f4 val, int S, int g, int t16) {
    int q0 = t16 * 4 - S;                    // first source position
    int t = q0 & 3;                          // row-uniform sub-word alignment

    // in-lane rotate-left of val by t: s[j] = val[(t+j)&3]
    bool b0 = (t & 1) != 0, b1 = (t & 2) != 0;
    float r0 = b1 ? val.z : val.x;
    float r1 = b1 ? val.w : val.y;
    float r2 = b1 ? val.x : val.z;
    float r3 = b1 ? val.y : val.w;
    float s0 = b0 ? r1 : r0;
    float s1 = b0 ? r2 : r1;
    float s2 = b0 ? r3 : r2;
    float s3 = b0 ? r0 : r3;

    int la0 = (q0    ) >> 2;  la0 = la0 < 0 ? 0 : la0;
    int la1 = (q0 + 1) >> 2;  la1 = la1 < 0 ? 0 : la1;
    int la2 = (q0 + 2) >> 2;  la2 = la2 < 0 ? 0 : la2;
    int la3 = (q0 + 3) >> 2;  la3 = la3 < 0 ? 0 : la3;
    int base = g * 16;

    float o0 = __shfl(s0, base + la0, 64);
    float o1 = __shfl(s1, base + la1, 64);
    float o2 = __shfl(s2, base + la2, 64);
    float o3 = __shfl(s3, base + la3, 64);

    f4 r;
    r.x = (q0 >= 0)  ? o0 : 0.0f;
    r.y = (q0 >= -1) ? o1 : 0.0f;
    r.z = (q0 >= -2) ? o2 : 0.0f;
    r.w = (q0 >= -3) ? o3 : 0.0f;
    return r;
}

// ---- phase 1: shift (6 floats/row) -> S code (1 byte/row) ----------------
__global__ __launch_bounds__(256)
void precompute_codes(const float* __restrict__ shift,
                      unsigned char* __restrict__ codes, int nrows) {
    int i = blockIdx.x * blockDim.x + threadIdx.x;
    int stride = gridDim.x * blockDim.x;
    for (int r = i; r < nrows; r += stride) {
        const float* s = shift + r * 6;
        int S = 0;
        S |= (s[0] > 0.5f) ? 32 : 0;
        S |= (s[1] > 0.5f) ? 16 : 0;
        S |= (s[2] > 0.5f) ?  8 : 0;
        S |= (s[3] > 0.5f) ?  4 : 0;
        S |= (s[4] > 0.5f) ?  2 : 0;
        S |= (s[5] > 0.5f) ?  1 : 0;
        codes[r] = (unsigned char)S;
    }
}

// ---- phase 2: streaming permute-copy -------------------------------------
__global__ __launch_bounds__(256)
void BarrelShifterRight64_main(const float* __restrict__ data,
                               const unsigned int* __restrict__ codes4,
                               float* __restrict__ out, int nwrows) {
    const int lane = threadIdx.x & 63;
    const int wib  = threadIdx.x >> 6;
    const int wpb  = blockDim.x >> 6;
    const int nw   = gridDim.x * wpb;
    const int w0   = blockIdx.x * wpb + wib;

    const f4* __restrict__ d4 = (const f4*)data;
    f4* __restrict__       o4 = (f4*)out;

    const int g   = lane >> 4;
    const int t16 = lane & 15;
    const int sh  = 8 * g;

    // software-pipeline the (tiny, uniform) code loads one iteration ahead
    unsigned cA = (w0 < nwrows)      ? codes4[w0]      : 0u;
    unsigned cB = (w0 + nw < nwrows) ? codes4[w0 + nw] : 0u;

    for (int w = w0; w < nwrows; w += 2 * nw) {
        const int w1 = w + nw;
        const bool have1 = w1 < nwrows;

        f4 vA = __builtin_nontemporal_load(&d4[w * 64 + lane]);
        f4 vB = (f4)(0.0f);
        if (have1) vB = __builtin_nontemporal_load(&d4[w1 * 64 + lane]);

        int SA = (int)((cA >> sh) & 63u);
        int SB = (int)((cB >> sh) & 63u);

        const int wA2 = w + 2 * nw, wB2 = w + 3 * nw;
        cA = (wA2 < nwrows) ? codes4[wA2] : 0u;
        cB = (wB2 < nwrows) ? codes4[wB2] : 0u;

        f4 oA = rowshift_S(vA, SA, g, t16);
        __builtin_nontemporal_store(oA, &o4[w * 64 + lane]);
        if (have1) {
            f4 oB = rowshift_S(vB, SB, g, t16);
            __builtin_nontemporal_store(oB, &o4[w1 * 64 + lane]);
        }
    }
}

// ---- fallback (R3 structure, single kernel) ------------------------------
__global__ __launch_bounds__(256)
void BarrelShifterRight64_fallback(const float* __restrict__ data,
                                   const float* __restrict__ shift,
                                   float* __restrict__ out, int nwrows) {
    const int lane = threadIdx.x & 63;
    const int wib  = threadIdx.x >> 6;
    const int wpb  = blockDim.x >> 6;
    const int nw   = gridDim.x * wpb;
    const int w0   = blockIdx.x * wpb + wib;

    const f4* __restrict__ d4 = (const f4*)data;
    f4* __restrict__       o4 = (f4*)out;

    const int g   = lane >> 4;
    const int t16 = lane & 15;

    for (int w = w0; w < nwrows; w += nw) {
        float sv = (lane < 24) ? shift[w * 24 + lane] : 0.0f;
        unsigned long long b = __ballot(sv > 0.5f);
        f4 v = __builtin_nontemporal_load(&d4[w * 64 + lane]);
        unsigned sub = (unsigned)(b >> (6 * g)) & 63u;
        int S = (int)(__brev(sub) >> 26);
        f4 o = rowshift_S(v, S, g, t16);
        __builtin_nontemporal_store(o, &o4[w * 64 + lane]);
    }
}

extern "C" void kernel_launch(void* const* d_in, const int* in_sizes, int n_in,
                              void* d_out, int out_size, void* d_ws, size_t ws_size,
                              hipStream_t stream) {
    const float* data  = (const float*)d_in[0];
    const float* shift = (const float*)d_in[1];
    float* out = (float*)d_out;

    const int nrows  = in_sizes[0] / 64;   // B
    const int nwrows = nrows / 4;          // 4 rows per wave

    const int block = 256;
    const int grid  = 2048;                // 8192 waves

    if (ws_size >= (size_t)nrows) {
        unsigned char* codes = (unsigned char*)d_ws;
        precompute_codes<<<grid, block, 0, stream>>>(shift, codes, nrows);
        BarrelShifterRight64_main<<<grid, block, 0, stream>>>(
            data, (const unsigned int*)codes, out, nwrows);
    } else {
        BarrelShifterRight64_fallback<<<grid, block, 0, stream>>>(data, shift, out, nwrows);
    }
}

// Round 9
// 168.224 us; speedup vs baseline: 1.4222x; 1.3157x over previous
//
#include <hip/hip_runtime.h>

// Barrel shift right each 64-float row by S = sum_j shift[j]*2^(5-j)
// (shift entries exactly 0/1):  out[row][k] = (k>=S) ? data[row][k-S] : 0.
//
// R9: one-shot dispatch — one wrow (4 rows, 1 KiB) per wave, giant grid,
// no grid-stride loop. Addresses follow the dispatcher's natural block
// order (the same front shape that lets the harness fill hit 6.7 TB/s).
// Body identical to R3's best: nt float4 load, ballot-derived S, in-lane
// rotate + 4 shfl permute, nt store.

typedef float f4 __attribute__((ext_vector_type(4)));

__global__ __launch_bounds__(256)
void BarrelShifterRight64_oneshot(const float* __restrict__ data,
                                  const float* __restrict__ shift,
                                  float* __restrict__ out,
                                  int nwrows) {
    const int lane = threadIdx.x & 63;
    const int wib  = threadIdx.x >> 6;
    const int w    = blockIdx.x * 4 + wib;      // 4 waves/block, 1 wrow/wave
    if (w >= nwrows) return;

    const f4* __restrict__ d4 = (const f4*)data;
    f4* __restrict__       o4 = (f4*)out;

    const int g   = lane >> 4;
    const int t16 = lane & 15;

    // 1 KiB coalesced data load + 96B shift load for the wave's 4 rows
    f4 val = __builtin_nontemporal_load(&d4[w * 64 + lane]);
    float sv = (lane < 24) ? shift[w * 24 + lane] : 0.0f;
    unsigned long long b = __ballot(sv > 0.5f);

    unsigned sub = (unsigned)(b >> (6 * g)) & 63u;
    int S  = (int)(__brev(sub) >> 26);          // MSB-first control word
    int q0 = t16 * 4 - S;
    int t  = q0 & 3;                            // row-uniform alignment

    // in-lane rotate-left of val by t: s[j] = val[(t+j)&3]
    bool b0 = (t & 1) != 0, b1 = (t & 2) != 0;
    float r0 = b1 ? val.z : val.x;
    float r1 = b1 ? val.w : val.y;
    float r2 = b1 ? val.x : val.z;
    float r3 = b1 ? val.y : val.w;
    float s0 = b0 ? r1 : r0;
    float s1 = b0 ? r2 : r1;
    float s2 = b0 ? r3 : r2;
    float s3 = b0 ? r0 : r3;

    int la0 = (q0    ) >> 2;  la0 = la0 < 0 ? 0 : la0;
    int la1 = (q0 + 1) >> 2;  la1 = la1 < 0 ? 0 : la1;
    int la2 = (q0 + 2) >> 2;  la2 = la2 < 0 ? 0 : la2;
    int la3 = (q0 + 3) >> 2;  la3 = la3 < 0 ? 0 : la3;
    int base = g * 16;

    float o0 = __shfl(s0, base + la0, 64);
    float o1 = __shfl(s1, base + la1, 64);
    float o2 = __shfl(s2, base + la2, 64);
    float o3 = __shfl(s3, base + la3, 64);

    f4 r;
    r.x = (q0 >= 0)  ? o0 : 0.0f;
    r.y = (q0 >= -1) ? o1 : 0.0f;
    r.z = (q0 >= -2) ? o2 : 0.0f;
    r.w = (q0 >= -3) ? o3 : 0.0f;

    __builtin_nontemporal_store(r, &o4[w * 64 + lane]);
}

extern "C" void kernel_launch(void* const* d_in, const int* in_sizes, int n_in,
                              void* d_out, int out_size, void* d_ws, size_t ws_size,
                              hipStream_t stream) {
    const float* data  = (const float*)d_in[0];
    const float* shift = (const float*)d_in[1];
    float* out = (float*)d_out;

    const int nrows  = in_sizes[0] / 64;   // B
    const int nwrows = nrows / 4;          // 4 rows per wave

    const int block = 256;                 // 4 waves/block
    const int grid  = (nwrows + 3) / 4;    // one wrow per wave, one-shot
    BarrelShifterRight64_oneshot<<<grid, block, 0, stream>>>(data, shift, out, nwrows);
}